// Round 5
// baseline (149.547 us; speedup 1.0000x reference)
//
#include <hip/hip_runtime.h>
#include <hip/hip_bf16.h>

// MANN fused v2: 4 launches. B=512, IN=480, OUT=400, HID=512, K=8 experts.
// Inputs fp32, output fp32.
// 1) gating_cvt: gating MLP (threads<128) + x->bf16 + ALL W fp32->bf16 (once;
//    kills the 8x redundant in-layer cvt of v1).
// 2-4) layer kernel: block = o-tile 16 x m-tile 64 (grid 256 = 32 o x 8 m,
//    o=idx&31 colocates same-W blocks per XCD). W(bf16) staged to LDS in
//    K-windows of 128 (2x32KB dbuf, XOR-swizzled, reg-prefetch pipeline).
//    Wave tile = 2 m-subtiles x 4 experts: per cl 2 A-frags (global, L1) +
//    4 B-frags (LDS) -> 8 MFMA (0.5KB/MFMA; LDS 103 B/cyc <= 128 budget).
//    Epilogue blends experts in-block via LDS (g-scale + g*bias + elu).

typedef __hip_bfloat16 bf16;
typedef unsigned short u16;
typedef __attribute__((ext_vector_type(8))) short bf16x8;
typedef __attribute__((ext_vector_type(4))) float f32x4;

__device__ __forceinline__ float elu1(float x) { return x > 0.f ? x : expm1f(x); }

__device__ __forceinline__ u16 cvt1(float v) {
    union { bf16 h; u16 u; } c;
    c.h = __float2bfloat16(v);          // RNE
    return c.u;
}

// ---------------- gating MLP + x-cvt + W-cvt ----------------
__global__ __launch_bounds__(256) void gating_cvt_kernel(
    const float* __restrict__ x, const int* __restrict__ idx_raw,
    const float* __restrict__ GW1, const float* __restrict__ Gb1,
    const float* __restrict__ GW2, const float* __restrict__ Gb2,
    const float* __restrict__ GW3, const float* __restrict__ Gb3,
    const float* __restrict__ Wk1, const float* __restrict__ Wk2,
    const float* __restrict__ Wk3,
    float* __restrict__ g, u16* __restrict__ xbf,
    u16* __restrict__ Wb1, u16* __restrict__ Wb2, u16* __restrict__ Wb3)
{
    __shared__ float xg[32];
    __shared__ float h1[128];
    __shared__ float h2[128];
    const int b = blockIdx.x;
    const int j = threadIdx.x;

    if (j < 32) {
        // gating_idx may arrive as int32 or int64; word1==0 iff int64
        int ii;
        if (idx_raw[1] == 0) ii = (int)((const long long*)idx_raw)[j];
        else                 ii = idx_raw[j];
        if (ii < 0 || ii >= 480) ii = 448 + j;  // memory-safety clamp
        xg[j] = x[(size_t)b * 480 + ii];
    }
    __syncthreads();

    if (j < 128) {
        float a = Gb1[j];
        #pragma unroll
        for (int i = 0; i < 32; ++i) a += xg[i] * GW1[i * 128 + j];
        h1[j] = elu1(a);
    }
    __syncthreads();

    if (j < 128) {
        float a2 = Gb2[j];
        #pragma unroll 8
        for (int i = 0; i < 128; ++i) a2 += h1[i] * GW2[i * 128 + j];
        h2[j] = elu1(a2);
    }
    __syncthreads();

    if (j < 8) {
        float a3 = Gb3[j];
        for (int i = 0; i < 128; ++i) a3 += h2[i] * GW3[i * 8 + j];
        g[b * 8 + j] = a3;  // no activation on blend coefficients
    }

    // x -> bf16 (this block's row)
    for (int i = j; i < 480; i += 256)
        xbf[b * 480 + i] = cvt1(x[b * 480 + i]);

    // W -> bf16: 712704 units of 8 elems = 512 blocks x 1392 units, exact.
    // ranges: Wk1 245760 | Wk2 262144 | Wk3 204800 units.
    #pragma unroll
    for (int jj = 0; jj < 6; ++jj) {
        const int local = jj * 256 + j;
        if (local >= 1392) break;
        const int u = b * 1392 + local;
        const float* src; u16* dst; size_t off;
        if (u < 245760)      { src = Wk1; dst = Wb1; off = (size_t)u * 8; }
        else if (u < 507904) { src = Wk2; dst = Wb2; off = (size_t)(u - 245760) * 8; }
        else                 { src = Wk3; dst = Wb3; off = (size_t)(u - 507904) * 8; }
        float4 a = *(const float4*)(src + off);
        float4 c = *(const float4*)(src + off + 4);
        union { u16 h[8]; uint4 v; } o;
        o.h[0] = cvt1(a.x); o.h[1] = cvt1(a.y); o.h[2] = cvt1(a.z); o.h[3] = cvt1(a.w);
        o.h[4] = cvt1(c.x); o.h[5] = cvt1(c.y); o.h[6] = cvt1(c.z); o.h[7] = cvt1(c.w);
        *(uint4*)(dst + off) = o.v;
    }
}

// ---------------- fused blended layer ----------------
// out[b,o] = act( sum_k g[b,k] * ( sum_i A[b,i]*Wk[k,o,i] + bk[k,o] ) )
template <int IDIM, int ODIM, bool ELU, typename OutT>
__global__ __launch_bounds__(256) void layer_kernel(
    const u16*  __restrict__ A,    // [512, IDIM] bf16
    const u16*  __restrict__ Wb,   // [8, ODIM, IDIM] bf16
    const float* __restrict__ bk,  // [8, ODIM] fp32
    const float* __restrict__ g,   // [512, 8] fp32
    OutT* __restrict__ out)        // [512, ODIM]
{
    constexpr int KW = 128;                       // K-window
    constexpr int NW = (IDIM + KW - 1) / KW;      // 4 for IDIM=480 and 512
    __shared__ u16 wbuf[2][128 * KW];             // 2 x 32 KB

    const int ot = blockIdx.x & 31;
    const int o0 = ot * 16;
    if (o0 >= ODIM) return;                       // ODIM=400: ot>=25 idle
    const int m0   = (blockIdx.x >> 5) * 64;
    const int tid  = threadIdx.x;
    const int wid  = tid >> 6;
    const int lane = tid & 63;
    const int n    = lane & 15;    // out col within tile / A row within 16
    const int quad = lane >> 4;
    const int w_m  = wid & 1;      // wave m-half (rows m0+32*w_m .. +31)
    const int w_e  = wid >> 1;     // wave expert-half (experts 4*w_e .. +3)
    const int e0   = w_e * 4;

    // staging: 2048 units of 8 bf16; unit u -> row r=u>>4 (r=e*16+nr),
    // chunk c=u&15; LDS chunk slot = c ^ (nr&7) (bank-conflict swizzle).
    uint4 lv[8];
    auto load_units = [&](int w) {
        const int w0 = w * KW;
        #pragma unroll
        for (int jj = 0; jj < 8; ++jj) {
            const int u = tid + 256 * jj;
            const int r = u >> 4, c = u & 15;
            const int e = r >> 4, nr = r & 15;
            if (w0 + c * 8 + 8 <= IDIM)
                lv[jj] = *(const uint4*)(Wb + ((size_t)(e * ODIM + o0 + nr)) * IDIM
                                            + w0 + c * 8);
            else
                lv[jj] = uint4{0u, 0u, 0u, 0u};
        }
    };
    auto write_units = [&](u16* buf) {
        #pragma unroll
        for (int jj = 0; jj < 8; ++jj) {
            const int u = tid + 256 * jj;
            const int r = u >> 4, c = u & 15;
            const int nr = r & 15;
            *(uint4*)(buf + r * KW + ((c ^ (nr & 7)) << 3)) = lv[jj];
        }
    };

    const f32x4 zero = {0.f, 0.f, 0.f, 0.f};
    f32x4 acc[2][4] = {{zero, zero, zero, zero}, {zero, zero, zero, zero}};

    load_units(0);
    write_units(wbuf[0]);
    __syncthreads();

    for (int w = 0; w < NW; ++w) {
        if (w + 1 < NW) load_units(w + 1);   // prefetch next window into regs

        const u16* buf = wbuf[w & 1];
        #pragma unroll
        for (int cl = 0; cl < KW / 32; ++cl) {
            const int i0 = w * KW + cl * 32;
            if (i0 >= IDIM) break;           // trims last window (IDIM=480)
            bf16x8 af[2];
            #pragma unroll
            for (int s = 0; s < 2; ++s)
                af[s] = *(const bf16x8*)(A + (size_t)(m0 + 16 * (2 * w_m + s) + n) * IDIM
                                           + i0 + quad * 8);
            const int cw = cl * 4 + quad;
            #pragma unroll
            for (int j = 0; j < 4; ++j) {
                bf16x8 bfr = *(const bf16x8*)(buf + ((e0 + j) * 16 + n) * KW
                                                  + ((cw ^ (n & 7)) << 3));
                acc[0][j] = __builtin_amdgcn_mfma_f32_16x16x32_bf16(af[0], bfr, acc[0][j], 0, 0, 0);
                acc[1][j] = __builtin_amdgcn_mfma_f32_16x16x32_bf16(af[1], bfr, acc[1][j], 0, 0, 0);
            }
        }

        if (w + 1 < NW) write_units(wbuf[(w + 1) & 1]);
        __syncthreads();
    }

    // ---- epilogue: wave blends its 4 experts; halves summed via LDS ----
    // C/D layout: col = lane&15 (=n), row = quad*4 + reg (batch).
    float* part = (float*)wbuf;              // [2][64][17] fp32, 8.7 KB
    float bkv[4];
    #pragma unroll
    for (int j = 0; j < 4; ++j) bkv[j] = bk[(e0 + j) * ODIM + o0 + n];

    #pragma unroll
    for (int s = 0; s < 2; ++s) {
        #pragma unroll
        for (int r = 0; r < 4; ++r) {
            const int lrow = 16 * (2 * w_m + s) + 4 * quad + r;
            const int grow = m0 + lrow;
            float v = 0.f;
            #pragma unroll
            for (int j = 0; j < 4; ++j)
                v += g[grow * 8 + e0 + j] * (acc[s][j][r] + bkv[j]);
            part[(w_e * 64 + lrow) * 17 + n] = v;
        }
    }
    __syncthreads();

    #pragma unroll
    for (int rr = 0; rr < 4; ++rr) {
        const int lrow = 16 * wid + 4 * quad + rr;
        float v = part[lrow * 17 + n] + part[(64 + lrow) * 17 + n];
        if (ELU) v = elu1(v);
        const int grow = m0 + lrow;
        if constexpr (__hip_internal::is_same<OutT, float>::value)
            out[(size_t)grow * ODIM + o0 + n] = v;
        else
            out[(size_t)grow * ODIM + o0 + n] = cvt1(v);
    }
}

extern "C" void kernel_launch(void* const* d_in, const int* in_sizes, int n_in,
                              void* d_out, int out_size, void* d_ws, size_t ws_size,
                              hipStream_t stream)
{
    const float* x   = (const float*)d_in[0];
    const int* gidx  = (const int*)d_in[1];
    const float* GW1 = (const float*)d_in[2];
    const float* Gb1 = (const float*)d_in[3];
    const float* GW2 = (const float*)d_in[4];
    const float* Gb2 = (const float*)d_in[5];
    const float* GW3 = (const float*)d_in[6];
    const float* Gb3 = (const float*)d_in[7];
    const float* Wk1 = (const float*)d_in[8];
    const float* bk1 = (const float*)d_in[9];
    const float* Wk2 = (const float*)d_in[10];
    const float* bk2 = (const float*)d_in[11];
    const float* Wk3 = (const float*)d_in[12];
    const float* bk3 = (const float*)d_in[13];

    char* ws  = (char*)d_ws;
    float* g  = (float*)ws;                          // @0      (16 KB)
    u16* xbf  = (u16*)(ws + (64 << 10));             // @64 KB  (480 KB)
    u16* A1   = (u16*)(ws + (1 << 20));              // @1 MB   (512 KB)
    u16* A2   = (u16*)(ws + (1 << 20) + (512 << 10));// @1.5 MB (512 KB)
    u16* Wb1  = (u16*)(ws + (2 << 20));              // @2 MB   (3.75 MB)
    u16* Wb2  = (u16*)(ws + (6 << 20));              // @6 MB   (4 MB)
    u16* Wb3  = (u16*)(ws + (10 << 20));             // @10 MB  (3.13 MB)

    gating_cvt_kernel<<<512, 256, 0, stream>>>(x, gidx, GW1, Gb1, GW2, Gb2,
                                               GW3, Gb3, Wk1, Wk2, Wk3,
                                               g, xbf, Wb1, Wb2, Wb3);

    layer_kernel<480, 512, true,  u16>  <<<256, 256, 0, stream>>>(xbf, Wb1, bk1, g, A1);
    layer_kernel<512, 512, true,  u16>  <<<256, 256, 0, stream>>>(A1,  Wb2, bk2, g, A2);
    layer_kernel<512, 400, false, float><<<256, 256, 0, stream>>>(A2,  Wb3, bk3, g,
                                                                  (float*)d_out);
}

// Round 6
// 135.789 us; speedup vs baseline: 1.1013x; 1.1013x over previous
//
#include <hip/hip_runtime.h>
#include <hip/hip_bf16.h>

// MANN fused v3: 4 launches. B=512, IN=480, OUT=400, HID=512, K=8 experts.
// Inputs fp32, output fp32.
// 1) gating_cvt: gating MLP + x->bf16 + ALL W fp32->bf16 (once).
// 2-4) layer kernel: block = o-tile 16 x m-tile 64 (grid 256 = 32 o x 8 m).
//    W staged to LDS via __builtin_amdgcn_global_load_lds width=16 (async,
//    NO staging VGPRs -- v2's reg-prefetch spilled 8.2MB of scratch/dispatch,
//    the 122us layer pathology). LDS dest is linear (wave-uniform base +
//    lane*16) so the bank-conflict XOR swizzle is applied on the GLOBAL
//    address side: LDS slot (r,slot) holds global chunk c = slot ^ (r&7);
//    ds_read_b128 B-frags then hit uniform bank residues (structural 8-way
//    only). K-windows of 128, 2x32KB double buffer. Wave tile = 2 m-subtiles
//    x 4 experts -> 8 MFMA per cl. Epilogue blends experts in-block via LDS.

typedef __hip_bfloat16 bf16;
typedef unsigned short u16;
typedef __attribute__((ext_vector_type(8))) short bf16x8;
typedef __attribute__((ext_vector_type(4))) float f32x4;

__device__ __forceinline__ float elu1(float x) { return x > 0.f ? x : expm1f(x); }

__device__ __forceinline__ u16 cvt1(float v) {
    union { bf16 h; u16 u; } c;
    c.h = __float2bfloat16(v);          // RNE
    return c.u;
}

__device__ __forceinline__ void async16(const u16* g, u16* l) {
    __builtin_amdgcn_global_load_lds(
        (const __attribute__((address_space(1))) void*)g,
        (__attribute__((address_space(3))) void*)l, 16, 0, 0);
}

// ---------------- gating MLP + x-cvt + W-cvt ----------------
__global__ __launch_bounds__(256) void gating_cvt_kernel(
    const float* __restrict__ x, const int* __restrict__ idx_raw,
    const float* __restrict__ GW1, const float* __restrict__ Gb1,
    const float* __restrict__ GW2, const float* __restrict__ Gb2,
    const float* __restrict__ GW3, const float* __restrict__ Gb3,
    const float* __restrict__ Wk1, const float* __restrict__ Wk2,
    const float* __restrict__ Wk3,
    float* __restrict__ g, u16* __restrict__ xbf,
    u16* __restrict__ Wb1, u16* __restrict__ Wb2, u16* __restrict__ Wb3)
{
    __shared__ float xg[32];
    __shared__ float h1[128];
    __shared__ float h2[128];
    const int b = blockIdx.x;
    const int j = threadIdx.x;

    if (j < 32) {
        // gating_idx may arrive as int32 or int64; word1==0 iff int64
        int ii;
        if (idx_raw[1] == 0) ii = (int)((const long long*)idx_raw)[j];
        else                 ii = idx_raw[j];
        if (ii < 0 || ii >= 480) ii = 448 + j;  // memory-safety clamp
        xg[j] = x[(size_t)b * 480 + ii];
    }
    __syncthreads();

    if (j < 128) {
        float a = Gb1[j];
        #pragma unroll
        for (int i = 0; i < 32; ++i) a += xg[i] * GW1[i * 128 + j];
        h1[j] = elu1(a);
    }
    __syncthreads();

    if (j < 128) {
        float a2 = Gb2[j];
        #pragma unroll 8
        for (int i = 0; i < 128; ++i) a2 += h1[i] * GW2[i * 128 + j];
        h2[j] = elu1(a2);
    }
    __syncthreads();

    if (j < 8) {
        float a3 = Gb3[j];
        for (int i = 0; i < 128; ++i) a3 += h2[i] * GW3[i * 8 + j];
        g[b * 8 + j] = a3;  // no activation on blend coefficients
    }

    // x -> bf16 (this block's row)
    for (int i = j; i < 480; i += 256)
        xbf[b * 480 + i] = cvt1(x[b * 480 + i]);

    // W -> bf16: 712704 units of 8 elems = 512 blocks x 1392 units, exact.
    // ranges: Wk1 245760 | Wk2 262144 | Wk3 204800 units.
    #pragma unroll
    for (int jj = 0; jj < 6; ++jj) {
        const int local = jj * 256 + j;
        if (local >= 1392) break;
        const int u = b * 1392 + local;
        const float* src; u16* dst; size_t off;
        if (u < 245760)      { src = Wk1; dst = Wb1; off = (size_t)u * 8; }
        else if (u < 507904) { src = Wk2; dst = Wb2; off = (size_t)(u - 245760) * 8; }
        else                 { src = Wk3; dst = Wb3; off = (size_t)(u - 507904) * 8; }
        float4 a = *(const float4*)(src + off);
        float4 c = *(const float4*)(src + off + 4);
        union { u16 h[8]; uint4 v; } o;
        o.h[0] = cvt1(a.x); o.h[1] = cvt1(a.y); o.h[2] = cvt1(a.z); o.h[3] = cvt1(a.w);
        o.h[4] = cvt1(c.x); o.h[5] = cvt1(c.y); o.h[6] = cvt1(c.z); o.h[7] = cvt1(c.w);
        *(uint4*)(dst + off) = o.v;
    }
}

// ---------------- fused blended layer ----------------
// out[b,o] = act( sum_k g[b,k] * ( sum_i A[b,i]*Wk[k,o,i] + bk[k,o] ) )
template <int IDIM, int ODIM, bool ELU, typename OutT>
__global__ __launch_bounds__(256) void layer_kernel(
    const u16*  __restrict__ A,    // [512, IDIM] bf16
    const u16*  __restrict__ Wb,   // [8, ODIM, IDIM] bf16
    const float* __restrict__ bk,  // [8, ODIM] fp32
    const float* __restrict__ g,   // [512, 8] fp32
    OutT* __restrict__ out)        // [512, ODIM]
{
    constexpr int KW = 128;                       // K-window (halfwords)
    constexpr int NW = (IDIM + KW - 1) / KW;      // 4 for IDIM=480 and 512
    __shared__ u16 wbuf[2][128 * KW];             // 2 x 32 KB

    const int ot = blockIdx.x & 31;
    const int o0 = ot * 16;
    if (o0 >= ODIM) return;                       // ODIM=400: ot>=25 idle
    const int m0   = (blockIdx.x >> 5) * 64;
    const int tid  = threadIdx.x;
    const int wid  = tid >> 6;
    const int lane = tid & 63;
    const int n    = lane & 15;    // out col within tile / A row within 16
    const int quad = lane >> 4;
    const int w_m  = wid & 1;      // wave m-half (rows m0+32*w_m .. +31)
    const int e0   = (wid >> 1) * 4;  // wave expert-quad

    // ---- async staging: 32 KB/window = 8 global_load_lds per wave.
    // instr t fills 16B-slots L = (wid*8+t)*64 + lane; L -> r=L>>4 (=e*16+nr),
    // slot=L&15; that slot holds global chunk c = slot ^ (nr&7). ----
    auto stage = [&](int w, u16* buf) {
        const int w0 = w * KW;
        #pragma unroll
        for (int t = 0; t < 8; ++t) {
            const int L = (wid * 8 + t) * 64 + lane;
            const int r = L >> 4, slot = L & 15;
            const int e = r >> 4, nr = r & 15;
            int koff = w0 + (slot ^ (nr & 7)) * 8;
            if (koff + 8 > IDIM) koff = IDIM - 8;   // clamp; never read
            async16(Wb + ((size_t)(e * ODIM + o0 + nr)) * IDIM + koff,
                    (u16*)buf + (size_t)(wid * 8 + t) * 512);
        }
    };

    const f32x4 zero = {0.f, 0.f, 0.f, 0.f};
    f32x4 acc[2][4] = {{zero, zero, zero, zero}, {zero, zero, zero, zero}};

    stage(0, wbuf[0]);
    __syncthreads();                 // barrier implies vmcnt(0) drain

    for (int w = 0; w < NW; ++w) {
        if (w + 1 < NW) stage(w + 1, wbuf[(w + 1) & 1]);  // in flight under MFMA

        const u16* buf = wbuf[w & 1];
        #pragma unroll
        for (int cl = 0; cl < KW / 32; ++cl) {
            const int i0 = w * KW + cl * 32;
            if (i0 >= IDIM) break;           // trims last window (IDIM=480)
            bf16x8 af[2];
            #pragma unroll
            for (int s = 0; s < 2; ++s)
                af[s] = *(const bf16x8*)(A + (size_t)(m0 + 16 * (2 * w_m + s) + n) * IDIM
                                           + i0 + quad * 8);
            const int cw = cl * 4 + quad;
            const int slot = (cw ^ (n & 7)) * 8;
            #pragma unroll
            for (int j = 0; j < 4; ++j) {
                bf16x8 bfr = *(const bf16x8*)(buf + ((e0 + j) * 16 + n) * KW + slot);
                acc[0][j] = __builtin_amdgcn_mfma_f32_16x16x32_bf16(af[0], bfr, acc[0][j], 0, 0, 0);
                acc[1][j] = __builtin_amdgcn_mfma_f32_16x16x32_bf16(af[1], bfr, acc[1][j], 0, 0, 0);
            }
        }
        __syncthreads();             // drains stage(w+1) + protects reuse
    }

    // ---- epilogue: wave blends its 4 experts; halves summed via LDS ----
    // C/D layout: col = lane&15 (=n), row = quad*4 + reg (batch).
    float* part = (float*)wbuf;              // [2][64][17] fp32, 8.7 KB
    float bkv[4];
    #pragma unroll
    for (int j = 0; j < 4; ++j) bkv[j] = bk[(e0 + j) * ODIM + o0 + n];

    #pragma unroll
    for (int s = 0; s < 2; ++s) {
        #pragma unroll
        for (int r = 0; r < 4; ++r) {
            const int lrow = 16 * (2 * w_m + s) + 4 * quad + r;
            const int grow = m0 + lrow;
            float v = 0.f;
            #pragma unroll
            for (int j = 0; j < 4; ++j)
                v += g[grow * 8 + e0 + j] * (acc[s][j][r] + bkv[j]);
            part[((wid >> 1) * 64 + lrow) * 17 + n] = v;
        }
    }
    __syncthreads();

    #pragma unroll
    for (int rr = 0; rr < 4; ++rr) {
        const int lrow = 16 * wid + 4 * quad + rr;
        float v = part[lrow * 17 + n] + part[(64 + lrow) * 17 + n];
        if (ELU) v = elu1(v);
        const int grow = m0 + lrow;
        if constexpr (__hip_internal::is_same<OutT, float>::value)
            out[(size_t)grow * ODIM + o0 + n] = v;
        else
            out[(size_t)grow * ODIM + o0 + n] = cvt1(v);
    }
}

extern "C" void kernel_launch(void* const* d_in, const int* in_sizes, int n_in,
                              void* d_out, int out_size, void* d_ws, size_t ws_size,
                              hipStream_t stream)
{
    const float* x   = (const float*)d_in[0];
    const int* gidx  = (const int*)d_in[1];
    const float* GW1 = (const float*)d_in[2];
    const float* Gb1 = (const float*)d_in[3];
    const float* GW2 = (const float*)d_in[4];
    const float* Gb2 = (const float*)d_in[5];
    const float* GW3 = (const float*)d_in[6];
    const float* Gb3 = (const float*)d_in[7];
    const float* Wk1 = (const float*)d_in[8];
    const float* bk1 = (const float*)d_in[9];
    const float* Wk2 = (const float*)d_in[10];
    const float* bk2 = (const float*)d_in[11];
    const float* Wk3 = (const float*)d_in[12];
    const float* bk3 = (const float*)d_in[13];

    char* ws  = (char*)d_ws;
    float* g  = (float*)ws;                          // @0      (16 KB)
    u16* xbf  = (u16*)(ws + (64 << 10));             // @64 KB  (480 KB)
    u16* A1   = (u16*)(ws + (1 << 20));              // @1 MB   (512 KB)
    u16* A2   = (u16*)(ws + (1 << 20) + (512 << 10));// @1.5 MB (512 KB)
    u16* Wb1  = (u16*)(ws + (2 << 20));              // @2 MB   (3.75 MB)
    u16* Wb2  = (u16*)(ws + (6 << 20));              // @6 MB   (4 MB)
    u16* Wb3  = (u16*)(ws + (10 << 20));             // @10 MB  (3.13 MB)

    gating_cvt_kernel<<<512, 256, 0, stream>>>(x, gidx, GW1, Gb1, GW2, Gb2,
                                               GW3, Gb3, Wk1, Wk2, Wk3,
                                               g, xbf, Wb1, Wb2, Wb3);

    layer_kernel<480, 512, true,  u16>  <<<256, 256, 0, stream>>>(xbf, Wb1, bk1, g, A1);
    layer_kernel<512, 512, true,  u16>  <<<256, 256, 0, stream>>>(A1,  Wb2, bk2, g, A2);
    layer_kernel<512, 400, false, float><<<256, 256, 0, stream>>>(A2,  Wb3, bk3, g,
                                                                  (float*)d_out);
}